// Round 7
// baseline (331.588 us; speedup 1.0000x reference)
//
#include <hip/hip_runtime.h>
#include <math.h>

#define NN 50000
#define NE 800000
#define F_IN 512
#define F_MID 256
#define F_OUT 40
#define LN_EPS 1e-5f

typedef float f32x4 __attribute__((ext_vector_type(4)));
typedef short s16x8 __attribute__((ext_vector_type(8)));
typedef unsigned short ushort;

__device__ __forceinline__ short f2bf(float f) {
    unsigned u = __float_as_uint(f);
    return (short)((u + 0x7FFF + ((u >> 16) & 1)) >> 16);  // RNE
}
__device__ __forceinline__ float bf2f(ushort u) {
    return __uint_as_float(((unsigned)u) << 16);
}

// ---------------- degree count (int) ----------------
__global__ void k_count(const int* __restrict__ ei, int* __restrict__ cnt) {
    int e = blockIdx.x * blockDim.x + threadIdx.x;
    if (e < NE) atomicAdd(&cnt[ei[NE + e]], 1);
}

// ---------------- hierarchical scan (+ dinv fused) ----------------
__global__ __launch_bounds__(1024) void k_scan1(const int* __restrict__ cnt,
                                                int* __restrict__ rs,
                                                int* __restrict__ bsum,
                                                float* __restrict__ dinv) {
    __shared__ int wsum[16];
    int t = threadIdx.x;
    int lane = t & 63, wid = t >> 6;
    int i = blockIdx.x * 1024 + t;
    int v = (i < NN) ? cnt[i] : 0;
    if (i < NN) dinv[i] = rsqrtf((float)(v + 1));  // +1 self loop
    int s = v;
#pragma unroll
    for (int o = 1; o < 64; o <<= 1) {
        int u = __shfl_up(s, o, 64);
        if (lane >= o) s += u;
    }
    if (lane == 63) wsum[wid] = s;
    __syncthreads();
    if (wid == 0 && lane < 16) {
        int w = wsum[lane];
        int ss = w;
#pragma unroll
        for (int o = 1; o < 16; o <<= 1) {
            int u = __shfl_up(ss, o, 16);
            if (lane >= o) ss += u;
        }
        wsum[lane] = ss - w;
    }
    __syncthreads();
    int incl = s + wsum[wid];
    if (i < NN) rs[i + 1] = incl;
    if (t == 1023) bsum[blockIdx.x] = incl;
}

__global__ void k_scan2(int* __restrict__ bsum, int* __restrict__ boff, int nb) {
    int t = threadIdx.x;  // 64 threads
    int v = (t < nb) ? bsum[t] : 0;
    int s = v;
#pragma unroll
    for (int o = 1; o < 64; o <<= 1) {
        int u = __shfl_up(s, o, 64);
        if (t >= o) s += u;
    }
    if (t < nb) boff[t] = s - v;  // exclusive
}

__global__ __launch_bounds__(1024) void k_scan3(int* __restrict__ rs,
                                                const int* __restrict__ boff,
                                                int* __restrict__ cursor) {
    int i = blockIdx.x * 1024 + threadIdx.x;
    if (i == 0) { rs[0] = 0; cursor[0] = 0; }
    if (i < NN) {
        int v = rs[i + 1] + boff[blockIdx.x];
        rs[i + 1] = v;
        if (i + 1 < NN) cursor[i + 1] = v;
    }
}

// ---------------- fill CSR: esrc sorted by dst ----------------
__global__ void k_fill(const int* __restrict__ ei, int* __restrict__ cursor,
                       int* __restrict__ esrc) {
    int e = blockIdx.x * blockDim.x + threadIdx.x;
    if (e >= NE) return;
    int src = ei[e];
    int dst = ei[NE + e];
    int pos = atomicAdd(&cursor[dst], 1);
    esrc[pos] = src;
}

// ---- W1 [512][256] -> B1p fragment-packed bf16: [(n*16+ks)*64+lane]*8 ----
__global__ void k_castW(const float* __restrict__ W, short* __restrict__ Wt) {
    int idx = blockIdx.x * 256 + threadIdx.x;  // 131072 total
    int j = idx & 7;
    int l = (idx >> 3) & 63;
    int ks = (idx >> 9) & 15;
    int n = idx >> 13;
    int k = ks * 32 + (l >> 4) * 8 + j;
    int col = n * 16 + (l & 15);
    Wt[idx] = f2bf(W[k * F_MID + col]);
}

// ---- W2 [256][40] -> B2p fragment-packed bf16 (48-col padded): [(n*8+ks)*64+lane]*8 ----
__global__ void k_castW2(const float* __restrict__ W, short* __restrict__ Wt) {
    int idx = blockIdx.x * 256 + threadIdx.x;  // 12288 total
    int j = idx & 7;
    int l = (idx >> 3) & 63;
    int ks = (idx >> 9) & 7;
    int n = idx >> 12;
    int k = ks * 32 + (l >> 4) * 8 + j;
    int col = n * 16 + (l & 15);
    Wt[idx] = (col < F_OUT) ? f2bf(W[k * F_OUT + col]) : (short)0;
}

// ---------------- GEMM1 (MFMA bf16, NO LDS): h1p = bf16((X@W1)*dinv) ----------------
// 4 waves/block, each wave an independent 32x128 tile (2m x 8n), K=512 (16 ks).
// A direct from global fp32 (convert in-reg), B from fragment-packed L2.
__global__ __launch_bounds__(256) void k_gemm1m(const float* __restrict__ X,
                                                const short* __restrict__ B1p,
                                                const float* __restrict__ dinv,
                                                ushort* __restrict__ H) {
    int t = threadIdx.x;
    int wv = t >> 6, lane = t & 63;
    int lm = lane & 15, kg = lane >> 4;
    int r0 = (blockIdx.x * 2 + (wv >> 1)) * 32;
    int nb = (wv & 1) * 8;  // n-tile base

    const float4* ap[2];
    bool rok[2];
#pragma unroll
    for (int m = 0; m < 2; ++m) {
        int row = r0 + m * 16 + lm;
        rok[m] = row < NN;
        ap[m] = (const float4*)(X + (size_t)row * F_IN + kg * 8);
    }
    const s16x8* bp = (const s16x8*)B1p;

    f32x4 acc[2][8];
#pragma unroll
    for (int m = 0; m < 2; ++m)
#pragma unroll
        for (int n = 0; n < 8; ++n) acc[m][n] = (f32x4){0.f, 0.f, 0.f, 0.f};

#pragma unroll
    for (int ks = 0; ks < 16; ++ks) {
        s16x8 af[2];
#pragma unroll
        for (int m = 0; m < 2; ++m) {
            float4 a0 = make_float4(0.f, 0.f, 0.f, 0.f);
            float4 a1 = make_float4(0.f, 0.f, 0.f, 0.f);
            if (rok[m]) { a0 = ap[m][ks * 8]; a1 = ap[m][ks * 8 + 1]; }
            s16x8 pk;
            pk[0] = f2bf(a0.x); pk[1] = f2bf(a0.y); pk[2] = f2bf(a0.z); pk[3] = f2bf(a0.w);
            pk[4] = f2bf(a1.x); pk[5] = f2bf(a1.y); pk[6] = f2bf(a1.z); pk[7] = f2bf(a1.w);
            af[m] = pk;
        }
        s16x8 bfr[8];
#pragma unroll
        for (int n = 0; n < 8; ++n)
            bfr[n] = bp[(size_t)((nb + n) * 16 + ks) * 64 + lane];
#pragma unroll
        for (int m = 0; m < 2; ++m)
#pragma unroll
            for (int n = 0; n < 8; ++n)
                acc[m][n] = __builtin_amdgcn_mfma_f32_16x16x32_bf16(af[m], bfr[n], acc[m][n], 0, 0, 0);
    }

#pragma unroll
    for (int m = 0; m < 2; ++m) {
#pragma unroll
        for (int reg = 0; reg < 4; ++reg) {
            int row = r0 + m * 16 + kg * 4 + reg;
            if (row < NN) {
                float s = dinv[row];
#pragma unroll
                for (int n = 0; n < 8; ++n)
                    H[(size_t)row * F_MID + (nb + n) * 16 + lm] = (ushort)f2bf(acc[m][n][reg] * s);
            }
        }
    }
}

// ---------------- fused gather-agg1 + dinv + bias + LN(256) + ELU -> bf16 ----------------
// wave per node; 2 lane-halves process 2 edges/iter, 16B/lane (s16x8), x2 unroll.
__global__ __launch_bounds__(256) void k_agg1(const int* __restrict__ rs,
                                              const int* __restrict__ esrc,
                                              const ushort* __restrict__ H,
                                              const float* __restrict__ dinv,
                                              const float* __restrict__ b,
                                              const float* __restrict__ g,
                                              const float* __restrict__ be,
                                              ushort* __restrict__ O) {
    int node = blockIdx.x * 4 + (threadIdx.x >> 6);
    if (node >= NN) return;
    int lane = threadIdx.x & 63;
    int half = lane >> 5;
    int c8 = (lane & 31) * 8;
    float acc[8] = {0.f, 0.f, 0.f, 0.f, 0.f, 0.f, 0.f, 0.f};
    if (half == 0) {
        s16x8 v = *(const s16x8*)&H[(size_t)node * F_MID + c8];
#pragma unroll
        for (int i = 0; i < 8; ++i) acc[i] = bf2f((ushort)v[i]);
    }
    int beg = rs[node], end = rs[node + 1];
    int j = beg + half;
    for (; j + 2 < end; j += 4) {
        int s0 = esrc[j], s1 = esrc[j + 2];
        s16x8 v0 = *(const s16x8*)&H[(size_t)s0 * F_MID + c8];
        s16x8 v1 = *(const s16x8*)&H[(size_t)s1 * F_MID + c8];
#pragma unroll
        for (int i = 0; i < 8; ++i) acc[i] += bf2f((ushort)v0[i]) + bf2f((ushort)v1[i]);
    }
    if (j < end) {
        int s0 = esrc[j];
        s16x8 v0 = *(const s16x8*)&H[(size_t)s0 * F_MID + c8];
#pragma unroll
        for (int i = 0; i < 8; ++i) acc[i] += bf2f((ushort)v0[i]);
    }
#pragma unroll
    for (int i = 0; i < 8; ++i) acc[i] += __shfl_xor(acc[i], 32, 64);

    float s0 = dinv[node];
    float v[8];
    float sum = 0.f, sq = 0.f;
#pragma unroll
    for (int i = 0; i < 8; ++i) {
        v[i] = s0 * acc[i] + b[c8 + i];
        sum += v[i];
        sq += v[i] * v[i];
    }
#pragma unroll
    for (int o = 32; o; o >>= 1) {
        sum += __shfl_xor(sum, o, 64);
        sq  += __shfl_xor(sq, o, 64);
    }
    // every column counted twice across the two identical halves -> /512
    float mu = sum * (1.0f / 512.0f);
    float var = sq * (1.0f / 512.0f) - mu * mu;
    float rstd = rsqrtf(var + LN_EPS);
    if (half == 0) {
        s16x8 o8;
#pragma unroll
        for (int i = 0; i < 8; ++i) {
            float y = (v[i] - mu) * rstd * g[c8 + i] + be[c8 + i];
            o8[i] = f2bf(y > 0.f ? y : expm1f(y));
        }
        *(s16x8*)&O[(size_t)node * F_MID + c8] = o8;
    }
}

// ---------------- GEMM2 (MFMA bf16, NO LDS): h2p[NN][48] = bf16((h1@W2)*dinv) ----------------
// 4 waves/block, each wave 32 rows x 48 cols (2m x 3n), K=256 (8 ks).
__global__ __launch_bounds__(256) void k_gemm2m(const ushort* __restrict__ Hin,
                                                const short* __restrict__ B2p,
                                                const float* __restrict__ dinv,
                                                ushort* __restrict__ H2) {
    int t = threadIdx.x;
    int wv = t >> 6, lane = t & 63;
    int lm = lane & 15, kg = lane >> 4;
    int r0 = blockIdx.x * 128 + wv * 32;

    const s16x8* ap[2];
    bool rok[2];
#pragma unroll
    for (int m = 0; m < 2; ++m) {
        int row = r0 + m * 16 + lm;
        rok[m] = row < NN;
        ap[m] = (const s16x8*)(Hin + (size_t)row * F_MID + kg * 8);
    }
    const s16x8* bp = (const s16x8*)B2p;

    f32x4 acc[2][3];
#pragma unroll
    for (int m = 0; m < 2; ++m)
#pragma unroll
        for (int n = 0; n < 3; ++n) acc[m][n] = (f32x4){0.f, 0.f, 0.f, 0.f};

#pragma unroll
    for (int ks = 0; ks < 8; ++ks) {
        s16x8 af[2];
#pragma unroll
        for (int m = 0; m < 2; ++m)
            af[m] = rok[m] ? ap[m][ks * 4] : (s16x8)0;
        s16x8 bfr[3];
#pragma unroll
        for (int n = 0; n < 3; ++n)
            bfr[n] = bp[(size_t)(n * 8 + ks) * 64 + lane];
#pragma unroll
        for (int m = 0; m < 2; ++m)
#pragma unroll
            for (int n = 0; n < 3; ++n)
                acc[m][n] = __builtin_amdgcn_mfma_f32_16x16x32_bf16(af[m], bfr[n], acc[m][n], 0, 0, 0);
    }

#pragma unroll
    for (int m = 0; m < 2; ++m) {
#pragma unroll
        for (int reg = 0; reg < 4; ++reg) {
            int row = r0 + m * 16 + kg * 4 + reg;
            if (row < NN) {
                float s = dinv[row];
#pragma unroll
                for (int n = 0; n < 3; ++n)
                    H2[(size_t)row * 48 + n * 16 + lm] = (ushort)f2bf(acc[m][n][reg] * s);
            }
        }
    }
}

// ------- fused gather-agg2 + dinv + bias + LN(40) + ELU + log_softmax -------
// wave per node; 8 edge-slots x 8 cols/lane on 48-padded rows.
__global__ __launch_bounds__(256) void k_agg2(const int* __restrict__ rs,
                                              const int* __restrict__ esrc,
                                              const ushort* __restrict__ H2,
                                              const float* __restrict__ dinv,
                                              const float* __restrict__ b,
                                              const float* __restrict__ g,
                                              const float* __restrict__ be,
                                              float* __restrict__ out) {
    int node = blockIdx.x * 4 + (threadIdx.x >> 6);
    if (node >= NN) return;
    int lane = threadIdx.x & 63;
    int gsl = lane >> 3;          // edge slot 0..7
    int c8 = (lane & 7) * 8;      // col base 0..56
    bool ld = c8 < 48;
    float acc[8] = {0.f, 0.f, 0.f, 0.f, 0.f, 0.f, 0.f, 0.f};
    if (gsl == 0 && ld) {
        s16x8 v = *(const s16x8*)&H2[(size_t)node * 48 + c8];
#pragma unroll
        for (int i = 0; i < 8; ++i) acc[i] = bf2f((ushort)v[i]);
    }
    int beg = rs[node], end = rs[node + 1];
    for (int j = beg + gsl; j < end; j += 8) {
        if (ld) {
            int s = esrc[j];
            s16x8 v = *(const s16x8*)&H2[(size_t)s * 48 + c8];
#pragma unroll
            for (int i = 0; i < 8; ++i) acc[i] += bf2f((ushort)v[i]);
        }
    }
#pragma unroll
    for (int i = 0; i < 8; ++i) {
        acc[i] += __shfl_xor(acc[i], 8, 64);
        acc[i] += __shfl_xor(acc[i], 16, 64);
        acc[i] += __shfl_xor(acc[i], 32, 64);
    }
    bool av = c8 < F_OUT;  // c8 in {0,8,16,24,32}
    float s0 = dinv[node];
    float v[8];
    float sum = 0.f, sq = 0.f;
#pragma unroll
    for (int i = 0; i < 8; ++i) {
        v[i] = av ? (s0 * acc[i] + b[c8 + i]) : 0.f;
        sum += v[i];
        sq += v[i] * v[i];
    }
#pragma unroll
    for (int o = 1; o < 8; o <<= 1) {
        sum += __shfl_xor(sum, o, 64);
        sq  += __shfl_xor(sq, o, 64);
    }
    float mu = sum * (1.0f / F_OUT);
    float var = sq * (1.0f / F_OUT) - mu * mu;
    float rstd = rsqrtf(var + LN_EPS);
    float el[8];
    float mx = -INFINITY;
#pragma unroll
    for (int i = 0; i < 8; ++i) {
        if (av) {
            float y = (v[i] - mu) * rstd * g[c8 + i] + be[c8 + i];
            el[i] = y > 0.f ? y : expm1f(y);
            mx = fmaxf(mx, el[i]);
        } else {
            el[i] = -INFINITY;
        }
    }
#pragma unroll
    for (int o = 1; o < 8; o <<= 1) mx = fmaxf(mx, __shfl_xor(mx, o, 64));
    float se = 0.f;
#pragma unroll
    for (int i = 0; i < 8; ++i)
        if (av) se += expf(el[i] - mx);
#pragma unroll
    for (int o = 1; o < 8; o <<= 1) se += __shfl_xor(se, o, 64);
    float lse = logf(se);
    if (gsl == 0 && av) {
        float o8[8];
#pragma unroll
        for (int i = 0; i < 8; ++i) o8[i] = el[i] - mx - lse;
        *(float4*)&out[(size_t)node * F_OUT + c8] = make_float4(o8[0], o8[1], o8[2], o8[3]);
        *(float4*)&out[(size_t)node * F_OUT + c8 + 4] = make_float4(o8[4], o8[5], o8[6], o8[7]);
    }
}

extern "C" void kernel_launch(void* const* d_in, const int* in_sizes, int n_in,
                              void* d_out, int out_size, void* d_ws, size_t ws_size,
                              hipStream_t stream) {
    const float* x   = (const float*)d_in[0];
    const int*   ei  = (const int*)d_in[1];
    const float* W1  = (const float*)d_in[2];
    const float* b1  = (const float*)d_in[3];
    const float* g1  = (const float*)d_in[4];
    const float* be1 = (const float*)d_in[5];
    const float* W2  = (const float*)d_in[6];
    const float* b2  = (const float*)d_in[7];
    const float* g2  = (const float*)d_in[8];
    const float* be2 = (const float*)d_in[9];
    float* out = (float*)d_out;

    char* p = (char*)d_ws;
    float* dinv = (float*)p;            p += 50000 * 4;
    ushort* h1p = (ushort*)p;           p += (size_t)NN * F_MID * 2;
    ushort* h1  = (ushort*)p;           p += (size_t)NN * F_MID * 2;
    ushort* h2p = (ushort*)p;           p += (size_t)NN * 48 * 2;
    short* B1p  = (short*)p;            p += (size_t)F_MID * F_IN * 2;
    short* B2p  = (short*)p;            p += 48 * 256 * 2;
    int* cnt      = (int*)p;            p += NN * 4;
    int* rowstart = (int*)p;            p += (NN + 1) * 4;
    int* cursor   = (int*)p;            p += NN * 4;
    int* bsum     = (int*)p;            p += 64 * 4;
    int* boff     = (int*)p;            p += 64 * 4;
    int* esrc     = (int*)p;

    const int NB = (NN + 1023) / 1024;  // 49

    hipMemsetAsync(cnt, 0, NN * sizeof(int), stream);
    k_count<<<(NE + 255) / 256, 256, 0, stream>>>(ei, cnt);
    k_scan1<<<NB, 1024, 0, stream>>>(cnt, rowstart, bsum, dinv);
    k_scan2<<<1, 64, 0, stream>>>(bsum, boff, NB);
    k_scan3<<<NB, 1024, 0, stream>>>(rowstart, boff, cursor);
    k_fill<<<(NE + 255) / 256, 256, 0, stream>>>(ei, cursor, esrc);
    k_castW<<<512, 256, 0, stream>>>(W1, B1p);
    k_castW2<<<48, 256, 0, stream>>>(W2, B2p);

    k_gemm1m<<<(NN + 63) / 64, 256, 0, stream>>>(x, B1p, dinv, h1p);
    k_agg1<<<(NN + 3) / 4, 256, 0, stream>>>(rowstart, esrc, h1p, dinv, b1, g1, be1, h1);
    k_gemm2m<<<(NN + 127) / 128, 256, 0, stream>>>(h1, B2p, dinv, h2p);
    k_agg2<<<(NN + 3) / 4, 256, 0, stream>>>(rowstart, esrc, h2p, dinv, b2, g2, be2, out);
}